// Round 2
// baseline (622.868 us; speedup 1.0000x reference)
//
#include <hip/hip_runtime.h>

// Problem constants (match reference file)
#define B_ 16
#define N_ 8192
#define M_ 2048
#define K_ 32
#define C_ 128

// out layout: pts [B,M,K,3] floats, then features [B,M,K,C] floats
#define PTS_ELEMS ((size_t)B_ * M_ * K_ * 3)   // 3,145,728

typedef float v4f __attribute__((ext_vector_type(4)));

// One block per (b,m) group, fused:
//   - wave 0 lanes 0..31: relative coords + max-norm for the K=32 neighbors
//     (shuffle butterfly over the 32-lane half-wave)
//   - all 256 threads: feature gather, K*C floats = 1024 float4 = 256 x 4.
//     Each thread owns column c4=tid&31 and rows k0+{0,8,16,24} -> 4
//     independent gather chains (MLP=4).
//
// XCD-affinity swizzle: hw block i lands on XCD i%8 (observed round-robin
// dispatch). Remap so XCD x exclusively processes batches 2x,2x+1; its
// random gathers then stay inside one 4.19 MB batch slice ~resident in its
// private 4 MB L2, instead of all 8 XCDs duplicating the same slice fetch.
//
// Feature output uses NON-TEMPORAL stores so the 537 MB write stream does
// not evict the gathered input rows from L2. Indices use NT loads (read-once).
__global__ __launch_bounds__(256) void fused_kernel(const float* __restrict__ input,
                                                    const float* __restrict__ points,
                                                    const float* __restrict__ next_pts,
                                                    const int* __restrict__ indices,
                                                    float* __restrict__ out_pts,
                                                    v4f* __restrict__ out_feat) {
    int i  = blockIdx.x;
    int bm = ((i & 7) << 12) | (i >> 3);   // bijective: grid 32768 % 8 == 0
    int b  = bm >> 11;                     // / M_
    int tid = threadIdx.x;

    const int* idxp = indices + (size_t)bm * K_;

    // ---- pts part: wave 0, lanes 0..31 (one lane per k) ----
    if (tid < K_) {
        int k   = tid;
        int idx = __builtin_nontemporal_load(idxp + k);
        const float* p  = points   + ((size_t)b * N_ + idx) * 3;
        const float* nq = next_pts + (size_t)bm * 3;

        float x = p[0] - nq[0];
        float y = p[1] - nq[1];
        float z = p[2] - nq[2];
        float sq = x * x + y * y + z * z;

        float mx = sq;
        #pragma unroll
        for (int off = 1; off <= 16; off <<= 1) {
            float o = __shfl_xor(mx, off, 64);   // stays within lanes 0..31
            mx = fmaxf(mx, o);
        }
        float maxi = sqrtf(mx);
        if (maxi == 0.0f) maxi = 1.0f;

        float* o = out_pts + ((size_t)bm * K_ + k) * 3;
        o[0] = x / maxi;
        o[1] = y / maxi;
        o[2] = z / maxi;
    }

    // ---- feat part: all 256 threads ----
    int c4 = tid & 31;             // C/4 = 32 columns of float4
    int k0 = tid >> 5;             // 0..7

    const v4f* in_b = (const v4f*)input + (size_t)b * ((size_t)N_ * (C_ / 4));
    v4f*       ob   = out_feat + (size_t)bm * (K_ * (C_ / 4));

    int i0 = __builtin_nontemporal_load(idxp + k0);
    int i1 = __builtin_nontemporal_load(idxp + k0 + 8);
    int i2 = __builtin_nontemporal_load(idxp + k0 + 16);
    int i3 = __builtin_nontemporal_load(idxp + k0 + 24);

    // 4 independent 16B gathers (rows reused ~8x on average within the slice)
    v4f v0 = in_b[(size_t)i0 * (C_ / 4) + c4];
    v4f v1 = in_b[(size_t)i1 * (C_ / 4) + c4];
    v4f v2 = in_b[(size_t)i2 * (C_ / 4) + c4];
    v4f v3 = in_b[(size_t)i3 * (C_ / 4) + c4];

    __builtin_nontemporal_store(v0, ob + ((k0     ) * (C_ / 4) + c4));
    __builtin_nontemporal_store(v1, ob + ((k0 +  8) * (C_ / 4) + c4));
    __builtin_nontemporal_store(v2, ob + ((k0 + 16) * (C_ / 4) + c4));
    __builtin_nontemporal_store(v3, ob + ((k0 + 24) * (C_ / 4) + c4));
}

extern "C" void kernel_launch(void* const* d_in, const int* in_sizes, int n_in,
                              void* d_out, int out_size, void* d_ws, size_t ws_size,
                              hipStream_t stream) {
    const float* input    = (const float*)d_in[0];
    const float* points   = (const float*)d_in[1];
    const float* next_pts = (const float*)d_in[2];
    const int*   indices  = (const int*)d_in[3];
    float* out = (float*)d_out;

    float* out_pts  = out;
    v4f*   out_feat = (v4f*)(out + PTS_ELEMS);  // 12.58 MB offset, 16B aligned

    int grid  = B_ * M_;   // 32768 blocks, one per (b,m)
    int block = 256;
    fused_kernel<<<grid, block, 0, stream>>>(input, points, next_pts, indices,
                                             out_pts, out_feat);
}

// Round 3
// 599.997 us; speedup vs baseline: 1.0381x; 1.0381x over previous
//
#include <hip/hip_runtime.h>

// Problem constants (match reference file)
#define B_ 16
#define N_ 8192
#define M_ 2048
#define K_ 32
#define C_ 128

// out layout: pts [B,M,K,3] floats, then features [B,M,K,C] floats
#define PTS_ELEMS ((size_t)B_ * M_ * K_ * 3)   // 3,145,728

typedef float v4f __attribute__((ext_vector_type(4)));

// One thread per (b,m,k). K=32 groups align to 32-lane halves of a wave64,
// so max-over-K is a 5-step shuffle butterfly (xor masks 1..16 stay in-group).
__global__ void pts_kernel(const float* __restrict__ points,
                           const float* __restrict__ next_pts,
                           const int* __restrict__ indices,
                           float* __restrict__ out_pts) {
    int t = blockIdx.x * blockDim.x + threadIdx.x;   // flat over B*M*K
    int bm = t >> 5;              // / K_
    int m  = bm & (M_ - 1);
    int b  = bm >> 11;            // / M_

    int idx = indices[t];
    const float* p  = points   + ((size_t)b * N_ + idx) * 3;
    const float* nq = next_pts + ((size_t)b * M_ + m) * 3;

    float x = p[0] - nq[0];
    float y = p[1] - nq[1];
    float z = p[2] - nq[2];
    float sq = x * x + y * y + z * z;

    float mx = sq;
    #pragma unroll
    for (int off = 1; off <= 16; off <<= 1) {
        float o = __shfl_xor(mx, off, 64);
        mx = fmaxf(mx, o);
    }
    float maxi = sqrtf(mx);
    if (maxi == 0.0f) maxi = 1.0f;

    float* o = out_pts + (size_t)t * 3;
    o[0] = x / maxi;
    o[1] = y / maxi;
    o[2] = z / maxi;
}

// One block per TWO (b,m) groups: 2*K*C floats = 2048 float4 = 256 threads x 8.
// Each thread owns column c4=tid&31 and rows k0+{0,8,16,24} of BOTH groups ->
// 8 independent gather chains (MLP=8, double R1's 4) to cover HBM latency
// (L3 is flushed by the harness's 2.2GB poison fill each iteration, so early
// gathers miss to HBM at ~900cy).
// Indices: one coalesced 256B load per wave (lane l reads idx[l]) + __shfl
// broadcast -- removes 8 dependent per-thread index loads from the chain.
// Feature output uses NON-TEMPORAL stores so the 537MB write stream doesn't
// evict gathered input rows from L2. Index/input loads stay cached (plain).
__global__ __launch_bounds__(256) void feat_kernel(const float* __restrict__ input,
                                                   const int* __restrict__ indices,
                                                   v4f* __restrict__ out_feat) {
    int bm0 = blockIdx.x << 1;      // even (b,m) group; bm1 = bm0+1 (same b)
    int b   = bm0 >> 11;            // / M_
    int tid = threadIdx.x;
    int c4  = tid & 31;             // C/4 = 32 columns of float4
    int k0  = tid >> 5;             // 0..7

    // 64 indices covering both groups, contiguous: one dword per lane
    int lane  = tid & 63;
    int idx_l = indices[(size_t)bm0 * K_ + lane];

    const v4f* in_b = (const v4f*)input + (size_t)b * ((size_t)N_ * (C_ / 4));
    v4f* ob0 = out_feat + (size_t)bm0 * (K_ * (C_ / 4));
    v4f* ob1 = ob0 + (K_ * (C_ / 4));

    // broadcast the 8 indices this thread needs (rows k0+8j of groups 0,1)
    int i00 = __shfl(idx_l, k0,      64);
    int i01 = __shfl(idx_l, k0 +  8, 64);
    int i02 = __shfl(idx_l, k0 + 16, 64);
    int i03 = __shfl(idx_l, k0 + 24, 64);
    int i10 = __shfl(idx_l, k0 + 32, 64);
    int i11 = __shfl(idx_l, k0 + 40, 64);
    int i12 = __shfl(idx_l, k0 + 48, 64);
    int i13 = __shfl(idx_l, k0 + 56, 64);

    // 8 independent 16B gathers (each half-wave reads a contiguous 512B row)
    v4f v00 = in_b[(size_t)i00 * (C_ / 4) + c4];
    v4f v01 = in_b[(size_t)i01 * (C_ / 4) + c4];
    v4f v02 = in_b[(size_t)i02 * (C_ / 4) + c4];
    v4f v03 = in_b[(size_t)i03 * (C_ / 4) + c4];
    v4f v10 = in_b[(size_t)i10 * (C_ / 4) + c4];
    v4f v11 = in_b[(size_t)i11 * (C_ / 4) + c4];
    v4f v12 = in_b[(size_t)i12 * (C_ / 4) + c4];
    v4f v13 = in_b[(size_t)i13 * (C_ / 4) + c4];

    // streaming (non-temporal) stores: bypass/evict-first in L2
    __builtin_nontemporal_store(v00, ob0 + ((k0     ) * (C_ / 4) + c4));
    __builtin_nontemporal_store(v01, ob0 + ((k0 +  8) * (C_ / 4) + c4));
    __builtin_nontemporal_store(v02, ob0 + ((k0 + 16) * (C_ / 4) + c4));
    __builtin_nontemporal_store(v03, ob0 + ((k0 + 24) * (C_ / 4) + c4));
    __builtin_nontemporal_store(v10, ob1 + ((k0     ) * (C_ / 4) + c4));
    __builtin_nontemporal_store(v11, ob1 + ((k0 +  8) * (C_ / 4) + c4));
    __builtin_nontemporal_store(v12, ob1 + ((k0 + 16) * (C_ / 4) + c4));
    __builtin_nontemporal_store(v13, ob1 + ((k0 + 24) * (C_ / 4) + c4));
}

extern "C" void kernel_launch(void* const* d_in, const int* in_sizes, int n_in,
                              void* d_out, int out_size, void* d_ws, size_t ws_size,
                              hipStream_t stream) {
    const float* input    = (const float*)d_in[0];
    const float* points   = (const float*)d_in[1];
    const float* next_pts = (const float*)d_in[2];
    const int*   indices  = (const int*)d_in[3];
    float* out = (float*)d_out;

    float* out_pts  = out;
    v4f*   out_feat = (v4f*)(out + PTS_ELEMS);  // 12.58 MB offset, 16B aligned

    // pts: B*M*K = 1,048,576 threads
    {
        int total = B_ * M_ * K_;
        int block = 256;
        int grid = total / block;   // 4096
        pts_kernel<<<grid, block, 0, stream>>>(points, next_pts, indices, out_pts);
    }
    // features: one block per two (b,m) groups -> 16384 blocks of 256 threads
    {
        int grid = (B_ * M_) / 2;   // 16384
        int block = 256;
        feat_kernel<<<grid, block, 0, stream>>>(input, indices, out_feat);
    }
}